// Round 4
// baseline (543.805 us; speedup 1.0000x reference)
//
#include <hip/hip_runtime.h>
#include <math.h>

typedef __attribute__((ext_vector_type(8))) short bf16x8;
typedef __attribute__((ext_vector_type(4))) float f32x4;
typedef __attribute__((ext_vector_type(4))) unsigned int u32x4;

#define BLK 256

// ws layout:
//   [0, 4096)           : W1 packed fp32, 128 cols x 8 floats {w0..w4, b1, 0, 0}
//   [4096, 20480)       : B hi-fragments, bf16(W)            (16 frags x 1024 B)
//   [20480, 36864)      : B lo-fragments, bf16(W - f32(hi))  (16 frags x 1024 B)
// frag F = mat*8 + nt*4 + kt (mat: 0=W21, 1=W22)
// ushort index within table = F*512 + lane*8 + j
// value = W[n = nt*16 + (lane&15)][k = kt*32 + (lane>>4)*8 + j]

__device__ __forceinline__ unsigned int rne_bf16_bits(float w) {
    unsigned int u = __builtin_bit_cast(unsigned int, w);
    u += 0x7fffu + ((u >> 16) & 1u);
    return u >> 16;
}

__global__ void setup_kernel(const float* __restrict__ W1, const float* __restrict__ b1,
                             const float* __restrict__ W21, const float* __restrict__ W22,
                             float* __restrict__ w1p,
                             unsigned short* __restrict__ frg_hi,
                             unsigned short* __restrict__ frg_lo)
{
    int t = blockIdx.x * blockDim.x + threadIdx.x;   // 0..4095
    if (t < 128) {
        int c = t;
        #pragma unroll
        for (int f = 0; f < 5; ++f) w1p[c * 8 + f] = W1[c * 5 + f];
        w1p[c * 8 + 5] = b1[c];
        w1p[c * 8 + 6] = 0.0f;
        w1p[c * 8 + 7] = 0.0f;
    }
    for (int e = t; e < 16 * 64 * 8; e += 4096) {
        int F = e >> 9, l = (e >> 3) & 63, j = e & 7;
        int mat = F >> 3, nt = (F >> 2) & 1, kt = F & 3;
        int n = nt * 16 + (l & 15);
        int k = kt * 32 + (l >> 4) * 8 + j;
        const float* W = mat ? W22 : W21;
        float w = W[n * 128 + k];
        unsigned int hi = rne_bf16_bits(w);
        float whi = __builtin_bit_cast(float, hi << 16);
        frg_hi[e] = (unsigned short)hi;
        frg_lo[e] = (unsigned short)rne_bf16_bits(w - whi);
    }
}

// One wave handles 16 rows per tile, 4 tiles per wave.
// Lane l: m = l&15 (row within tile), q = l>>4 (k-quad).
// Phase A (VALU): lane computes h1[m][kt*32+q*8+j] -- exactly its own MFMA
// A-fragment elements. No LDS anywhere.
__global__ __launch_bounds__(BLK, 4) void barriernet_kernel(
    const float* __restrict__ x,
    const float* __restrict__ mean, const float* __restrict__ stdv,
    const float* __restrict__ b21, const float* __restrict__ b22,
    const float* __restrict__ W31, const float* __restrict__ b31,
    const float* __restrict__ W32, const float* __restrict__ b32,
    const float* __restrict__ w1p,
    const unsigned short* __restrict__ frg_hi,
    const unsigned short* __restrict__ frg_lo,
    float* __restrict__ out)
{
    const int lane = threadIdx.x & 63;
    const int m    = lane & 15;
    const int q    = lane >> 4;
    const int waveId = (blockIdx.x * BLK + threadIdx.x) >> 6;

    float sm_s[5], sm_m[5];
    #pragma unroll
    for (int f = 0; f < 5; ++f) { sm_s[f] = stdv[f]; sm_m[f] = mean[f]; }
    const float b21v0 = b21[m],      b21v1 = b21[16 + m];
    const float b22v0 = b22[m],      b22v1 = b22[16 + m];
    const float w31v0 = W31[m],      w31v1 = W31[16 + m];
    const float w32v0 = W32[m],      w32v1 = W32[16 + m];
    const float b31s  = b31[0],      b32s  = b32[0];

    // frag F, lane l -> element F*64 + l   (frag = 1024 B = 64 x u32x4)
    const u32x4* fhp = (const u32x4*)frg_hi;
    const u32x4* flp = (const u32x4*)frg_lo;

    #pragma unroll 1
    for (int it = 0; it < 4; ++it) {
        const long tile    = (long)waveId * 4 + it;
        const long rowbase = tile * 16;

        float xf[5];
        #pragma unroll
        for (int f = 0; f < 5; ++f) xf[f] = x[(rowbase + m) * 5 + f];

        // ---- Phase A: layer 1 directly into A-fragment layout (RNE pack) ----
        unsigned int au[4][4];   // [ktile][dword] : 8 bf16 per ktile
        #pragma unroll
        for (int t = 0; t < 4; ++t) {
            #pragma unroll
            for (int p = 0; p < 4; ++p) {
                float hv[2];
                #pragma unroll
                for (int s = 0; s < 2; ++s) {
                    const int c = t * 32 + q * 8 + p * 2 + s;
                    const float4 w4 = *(const float4*)(w1p + c * 8);
                    const float2 w2 = *(const float2*)(w1p + c * 8 + 4);
                    float h = w2.y;                       // b1[c]
                    h = fmaf(xf[0], w4.x, h);
                    h = fmaf(xf[1], w4.y, h);
                    h = fmaf(xf[2], w4.z, h);
                    h = fmaf(xf[3], w4.w, h);
                    h = fmaf(xf[4], w2.x, h);
                    hv[s] = fmaxf(h, 0.0f);
                }
                // RNE pack: even element -> low half, odd -> high half
                au[t][p] = rne_bf16_bits(hv[0]) | (rne_bf16_bits(hv[1]) << 16);
            }
        }

        // ---- GEMM2 on matrix cores (B = hi + lo bf16 split) ----
        f32x4 a21_0 = { b21v0, b21v0, b21v0, b21v0 };
        f32x4 a21_1 = { b21v1, b21v1, b21v1, b21v1 };
        f32x4 a22_0 = { b22v0, b22v0, b22v0, b22v0 };
        f32x4 a22_1 = { b22v1, b22v1, b22v1, b22v1 };
        #pragma unroll
        for (int kt = 0; kt < 4; ++kt) {
            u32x4 t4 = { au[kt][0], au[kt][1], au[kt][2], au[kt][3] };
            bf16x8 a = __builtin_bit_cast(bf16x8, t4);
            const int F210 = (0*8 + 0*4 + kt) * 64 + lane;
            const int F211 = (0*8 + 1*4 + kt) * 64 + lane;
            const int F220 = (1*8 + 0*4 + kt) * 64 + lane;
            const int F221 = (1*8 + 1*4 + kt) * 64 + lane;
            bf16x8 h210 = __builtin_bit_cast(bf16x8, fhp[F210]);
            bf16x8 h211 = __builtin_bit_cast(bf16x8, fhp[F211]);
            bf16x8 h220 = __builtin_bit_cast(bf16x8, fhp[F220]);
            bf16x8 h221 = __builtin_bit_cast(bf16x8, fhp[F221]);
            bf16x8 l210 = __builtin_bit_cast(bf16x8, flp[F210]);
            bf16x8 l211 = __builtin_bit_cast(bf16x8, flp[F211]);
            bf16x8 l220 = __builtin_bit_cast(bf16x8, flp[F220]);
            bf16x8 l221 = __builtin_bit_cast(bf16x8, flp[F221]);
            a21_0 = __builtin_amdgcn_mfma_f32_16x16x32_bf16(a, h210, a21_0, 0, 0, 0);
            a21_1 = __builtin_amdgcn_mfma_f32_16x16x32_bf16(a, h211, a21_1, 0, 0, 0);
            a22_0 = __builtin_amdgcn_mfma_f32_16x16x32_bf16(a, h220, a22_0, 0, 0, 0);
            a22_1 = __builtin_amdgcn_mfma_f32_16x16x32_bf16(a, h221, a22_1, 0, 0, 0);
            a21_0 = __builtin_amdgcn_mfma_f32_16x16x32_bf16(a, l210, a21_0, 0, 0, 0);
            a21_1 = __builtin_amdgcn_mfma_f32_16x16x32_bf16(a, l211, a21_1, 0, 0, 0);
            a22_0 = __builtin_amdgcn_mfma_f32_16x16x32_bf16(a, l220, a22_0, 0, 0, 0);
            a22_1 = __builtin_amdgcn_mfma_f32_16x16x32_bf16(a, l221, a22_1, 0, 0, 0);
        }

        // ---- Heads: relu + dot with W31/W32, butterfly-reduce over 16 cols ----
        float p31[4], p32[4];
        #pragma unroll
        for (int r = 0; r < 4; ++r) {
            p31[r] = fmaf(fmaxf(a21_0[r], 0.0f), w31v0, fmaxf(a21_1[r], 0.0f) * w31v1);
            p32[r] = fmaf(fmaxf(a22_0[r], 0.0f), w32v0, fmaxf(a22_1[r], 0.0f) * w32v1);
        }
        #pragma unroll
        for (int d = 1; d < 16; d <<= 1) {
            #pragma unroll
            for (int r = 0; r < 4; ++r) {
                p31[r] += __shfl_xor(p31[r], d);
                p32[r] += __shfl_xor(p32[r], d);
            }
        }

        // ---- Epilogue: rows q*4+rl live on writer lanes rl = lane&15 < 4 ----
        const int rl = lane & 15;
        const int R  = q * 4 + (rl & 3);          // row within tile
        const int src = (lane & 48) | R;          // lane holding xf for row R
        float xr[5];
        #pragma unroll
        for (int f = 0; f < 5; ++f) xr[f] = __shfl(xf[f], src);

        if (rl < 4) {
            const float s31 = (rl & 2) ? ((rl & 1) ? p31[3] : p31[2])
                                       : ((rl & 1) ? p31[1] : p31[0]);
            const float s32 = (rl & 2) ? ((rl & 1) ? p32[3] : p32[2])
                                       : ((rl & 1) ? p32[1] : p32[0]);
            const float x31 = s31 + b31s;
            const float z   = s32 + b32s;
            const float x32 = 4.0f / (1.0f + __expf(-z));
            float x0[5];
            #pragma unroll
            for (int f = 0; f < 5; ++f) x0[f] = fmaf(xr[f], sm_s[f], sm_m[f]);
            const float h_ineq = (x0[1] - x0[3]) + x32 * (x0[0] - x0[2] - 1.8f * x0[3]);
            const float u_unc  = -x31;
            const float u      = (1.8f * u_unc <= h_ineq) ? u_unc : (h_ineq / 1.8f);
            out[rowbase + R] = u;
        }
    }
}

extern "C" void kernel_launch(void* const* d_in, const int* in_sizes, int n_in,
                              void* d_out, int out_size, void* d_ws, size_t ws_size,
                              hipStream_t stream) {
    const float* x    = (const float*)d_in[0];
    const float* mean = (const float*)d_in[1];
    const float* stdv = (const float*)d_in[2];
    const float* W1   = (const float*)d_in[3];
    const float* b1   = (const float*)d_in[4];
    const float* W21  = (const float*)d_in[5];
    const float* b21  = (const float*)d_in[6];
    const float* W22  = (const float*)d_in[7];
    const float* b22  = (const float*)d_in[8];
    const float* W31  = (const float*)d_in[9];
    const float* b31  = (const float*)d_in[10];
    const float* W32  = (const float*)d_in[11];
    const float* b32  = (const float*)d_in[12];
    float* out = (float*)d_out;

    float* w1p = (float*)d_ws;
    unsigned short* frg_hi = (unsigned short*)((char*)d_ws + 4096);
    unsigned short* frg_lo = (unsigned short*)((char*)d_ws + 20480);

    setup_kernel<<<16, 256, 0, stream>>>(W1, b1, W21, W22, w1p, frg_hi, frg_lo);

    // 524288 rows / 16 = 32768 tiles; 2048 blocks * 4 waves * 4 tiles
    barriernet_kernel<<<2048, BLK, 0, stream>>>(
        x, mean, stdv, b21, b22, W31, b31, W32, b32, w1p, frg_hi, frg_lo, out);
}

// Round 5
// 129.065 us; speedup vs baseline: 4.2134x; 4.2134x over previous
//
#include <hip/hip_runtime.h>
#include <math.h>

typedef __attribute__((ext_vector_type(8))) short bf16x8;
typedef __attribute__((ext_vector_type(4))) float f32x4;
typedef __attribute__((ext_vector_type(4))) unsigned int u32x4;

#define BLK 256

// ws layout:
//   [0, 4096)      : W1 quad-packed fp32. For neuron c = t*32 + q*8 + j:
//                    float idx = ((t*8 + j)*4 + q)*8 -> {w0..w4, b1, 0, 0}.
//                    The 4 q-variants of one (t,j) share one 128-B line.
//   [4096, 20480)  : B hi-fragments, bf16(W)           (16 frags x 1024 B)
//   [20480, 36864) : B lo-fragments, bf16(W - f32(hi)) (16 frags x 1024 B)
// frag F = mat*8 + nt*4 + kt (mat: 0=W21, 1=W22)
// ushort index within table = F*512 + lane*8 + jj
// value = W[n = nt*16 + (lane&15)][k = kt*32 + (lane>>4)*8 + jj]

__device__ __forceinline__ unsigned int rne_bf16_bits(float w) {
    unsigned int u = __builtin_bit_cast(unsigned int, w);
    u += 0x7fffu + ((u >> 16) & 1u);
    return u >> 16;
}

__global__ void setup_kernel(const float* __restrict__ W1, const float* __restrict__ b1,
                             const float* __restrict__ W21, const float* __restrict__ W22,
                             float* __restrict__ w1q,
                             unsigned short* __restrict__ frg_hi,
                             unsigned short* __restrict__ frg_lo)
{
    int t = blockIdx.x * blockDim.x + threadIdx.x;   // 0..4095
    if (t < 128) {
        int c  = t;
        int tt = c >> 5, r = c & 31, qq = r >> 3, j = r & 7;
        float* dst = w1q + ((tt * 8 + j) * 4 + qq) * 8;
        #pragma unroll
        for (int f = 0; f < 5; ++f) dst[f] = W1[c * 5 + f];
        dst[5] = b1[c];
        dst[6] = 0.0f;
        dst[7] = 0.0f;
    }
    for (int e = t; e < 16 * 64 * 8; e += 4096) {
        int F = e >> 9, l = (e >> 3) & 63, j = e & 7;
        int mat = F >> 3, nt = (F >> 2) & 1, kt = F & 3;
        int n = nt * 16 + (l & 15);
        int k = kt * 32 + (l >> 4) * 8 + j;
        const float* W = mat ? W22 : W21;
        float w = W[n * 128 + k];
        unsigned int hi = rne_bf16_bits(w);
        float whi = __builtin_bit_cast(float, hi << 16);
        frg_hi[e] = (unsigned short)hi;
        frg_lo[e] = (unsigned short)rne_bf16_bits(w - whi);
    }
}

// Block = 4 waves, 256 contiguous rows. Wave handles 4 row-tiles of 16,
// processed as 2 iterations x 2 tiles (register-blocked so each LDS
// B-fragment read feeds 2 MFMAs). B tables live in LDS; W1 in L1 via the
// quad-packed w1q layout; x staged in LDS. `zero` (==0 at runtime) makes
// table addresses it-dependent so LICM cannot hoist them into registers
// (the R4 spill disaster).
__global__ __launch_bounds__(BLK, 3) void barriernet_kernel(
    const float* __restrict__ x,
    const float* __restrict__ mean, const float* __restrict__ stdv,
    const float* __restrict__ b21, const float* __restrict__ b22,
    const float* __restrict__ W31, const float* __restrict__ b31,
    const float* __restrict__ W32, const float* __restrict__ b32,
    const float* __restrict__ w1q, const u32x4* __restrict__ frg,
    float* __restrict__ out, int zero)
{
    __shared__ u32x4 ldsF[2048];    // hi [0,1024), lo [1024,2048)
    __shared__ float ldsX[1280];    // 256 rows x 5

    const int tid = threadIdx.x;
    #pragma unroll
    for (int i = 0; i < 8; ++i) ldsF[tid + i * BLK] = frg[tid + i * BLK];
    const float* xblk = x + (size_t)blockIdx.x * 1280;
    #pragma unroll
    for (int i = 0; i < 5; ++i) ldsX[tid + i * BLK] = xblk[tid + i * BLK];

    const int lane = tid & 63;
    const int wave = tid >> 6;
    const int m    = lane & 15;
    const int q    = lane >> 4;

    float sm_s[5], sm_m[5];
    #pragma unroll
    for (int f = 0; f < 5; ++f) { sm_s[f] = stdv[f]; sm_m[f] = mean[f]; }
    const float b21v0 = b21[m], b21v1 = b21[16 + m];
    const float b22v0 = b22[m], b22v1 = b22[16 + m];
    const float w31v0 = W31[m], w31v1 = W31[16 + m];
    const float w32v0 = W32[m], w32v1 = W32[16 + m];
    const float b31s  = b31[0], b32s  = b32[0];

    __syncthreads();

    const size_t row0 = (size_t)blockIdx.x * 256;

    #pragma unroll 1
    for (int it = 0; it < 2; ++it) {
        const int tl0 = wave * 4 + it * 2;         // local tiles tl0, tl0+1

        float xf[2][5];
        #pragma unroll
        for (int T = 0; T < 2; ++T)
            #pragma unroll
            for (int f = 0; f < 5; ++f)
                xf[T][f] = ldsX[((tl0 + T) * 16 + m) * 5 + f];

        // ---- Phase A: layer 1 into A-fragment layout for both tiles ----
        const float* wz = w1q + it * zero;         // anti-hoist
        unsigned int au[2][4][4];
        #pragma unroll
        for (int t = 0; t < 4; ++t) {
            #pragma unroll
            for (int p = 0; p < 4; ++p) {
                const int g0 = ((t * 8 + p * 2) * 4 + q) * 8;
                const float4 a0 = *(const float4*)(wz + g0);
                const float4 a1 = *(const float4*)(wz + g0 + 4);
                const float4 c0 = *(const float4*)(wz + g0 + 32);
                const float4 c1 = *(const float4*)(wz + g0 + 36);
                #pragma unroll
                for (int T = 0; T < 2; ++T) {
                    float h0 = a1.y;
                    h0 = fmaf(xf[T][0], a0.x, h0);
                    h0 = fmaf(xf[T][1], a0.y, h0);
                    h0 = fmaf(xf[T][2], a0.z, h0);
                    h0 = fmaf(xf[T][3], a0.w, h0);
                    h0 = fmaf(xf[T][4], a1.x, h0);
                    h0 = fmaxf(h0, 0.0f);
                    float h1 = c1.y;
                    h1 = fmaf(xf[T][0], c0.x, h1);
                    h1 = fmaf(xf[T][1], c0.y, h1);
                    h1 = fmaf(xf[T][2], c0.z, h1);
                    h1 = fmaf(xf[T][3], c0.w, h1);
                    h1 = fmaf(xf[T][4], c1.x, h1);
                    h1 = fmaxf(h1, 0.0f);
                    au[T][t][p] = rne_bf16_bits(h0) | (rne_bf16_bits(h1) << 16);
                }
            }
        }

        // ---- GEMM2 on matrix cores (B = hi + lo bf16, from LDS) ----
        f32x4 acc[2][4];
        #pragma unroll
        for (int T = 0; T < 2; ++T) {
            acc[T][0] = f32x4{ b21v0, b21v0, b21v0, b21v0 };
            acc[T][1] = f32x4{ b21v1, b21v1, b21v1, b21v1 };
            acc[T][2] = f32x4{ b22v0, b22v0, b22v0, b22v0 };
            acc[T][3] = f32x4{ b22v1, b22v1, b22v1, b22v1 };
        }
        const int fz = it * zero;                  // anti-hoist
        #pragma unroll
        for (int kt = 0; kt < 4; ++kt) {
            bf16x8 bh[4], bl[4];
            #pragma unroll
            for (int c = 0; c < 4; ++c) {          // c = mat*2 + nt
                const int F = (c >> 1) * 8 + (c & 1) * 4 + kt;
                bh[c] = __builtin_bit_cast(bf16x8, ldsF[F * 64 + lane + fz]);
                bl[c] = __builtin_bit_cast(bf16x8, ldsF[1024 + F * 64 + lane + fz]);
            }
            #pragma unroll
            for (int T = 0; T < 2; ++T) {
                u32x4 t4 = { au[T][kt][0], au[T][kt][1], au[T][kt][2], au[T][kt][3] };
                bf16x8 a = __builtin_bit_cast(bf16x8, t4);
                #pragma unroll
                for (int c = 0; c < 4; ++c)
                    acc[T][c] = __builtin_amdgcn_mfma_f32_16x16x32_bf16(a, bh[c], acc[T][c], 0, 0, 0);
                #pragma unroll
                for (int c = 0; c < 4; ++c)
                    acc[T][c] = __builtin_amdgcn_mfma_f32_16x16x32_bf16(a, bl[c], acc[T][c], 0, 0, 0);
            }
        }

        // ---- Heads + epilogue per tile ----
        #pragma unroll
        for (int T = 0; T < 2; ++T) {
            float p31[4], p32[4];
            #pragma unroll
            for (int r = 0; r < 4; ++r) {
                p31[r] = fmaf(fmaxf(acc[T][0][r], 0.0f), w31v0, fmaxf(acc[T][1][r], 0.0f) * w31v1);
                p32[r] = fmaf(fmaxf(acc[T][2][r], 0.0f), w32v0, fmaxf(acc[T][3][r], 0.0f) * w32v1);
            }
            #pragma unroll
            for (int d = 1; d < 16; d <<= 1) {
                #pragma unroll
                for (int r = 0; r < 4; ++r) {
                    p31[r] += __shfl_xor(p31[r], d);
                    p32[r] += __shfl_xor(p32[r], d);
                }
            }

            const int rl = lane & 15;
            const int R  = q * 4 + (rl & 3);       // row within tile
            if (rl < 4) {
                const float s31 = (rl & 2) ? ((rl & 1) ? p31[3] : p31[2])
                                           : ((rl & 1) ? p31[1] : p31[0]);
                const float s32 = (rl & 2) ? ((rl & 1) ? p32[3] : p32[2])
                                           : ((rl & 1) ? p32[1] : p32[0]);
                const float x31 = s31 + b31s;
                const float z   = s32 + b32s;
                const float x32 = 4.0f / (1.0f + __expf(-z));
                float x0[5];
                #pragma unroll
                for (int f = 0; f < 5; ++f)
                    x0[f] = fmaf(ldsX[((tl0 + T) * 16 + R) * 5 + f], sm_s[f], sm_m[f]);
                const float h_ineq = (x0[1] - x0[3]) + x32 * (x0[0] - x0[2] - 1.8f * x0[3]);
                const float u_unc  = -x31;
                const float u      = (1.8f * u_unc <= h_ineq) ? u_unc : (h_ineq / 1.8f);
                out[row0 + (tl0 + T) * 16 + R] = u;
            }
        }
    }
}

extern "C" void kernel_launch(void* const* d_in, const int* in_sizes, int n_in,
                              void* d_out, int out_size, void* d_ws, size_t ws_size,
                              hipStream_t stream) {
    const float* x    = (const float*)d_in[0];
    const float* mean = (const float*)d_in[1];
    const float* stdv = (const float*)d_in[2];
    const float* W1   = (const float*)d_in[3];
    const float* b1   = (const float*)d_in[4];
    const float* W21  = (const float*)d_in[5];
    const float* b21  = (const float*)d_in[6];
    const float* W22  = (const float*)d_in[7];
    const float* b22  = (const float*)d_in[8];
    const float* W31  = (const float*)d_in[9];
    const float* b31  = (const float*)d_in[10];
    const float* W32  = (const float*)d_in[11];
    const float* b32  = (const float*)d_in[12];
    float* out = (float*)d_out;

    float* w1q = (float*)d_ws;
    unsigned short* frg_hi = (unsigned short*)((char*)d_ws + 4096);
    unsigned short* frg_lo = (unsigned short*)((char*)d_ws + 20480);

    setup_kernel<<<16, 256, 0, stream>>>(W1, b1, W21, W22, w1q, frg_hi, frg_lo);

    // 524288 rows / 256 rows-per-block = 2048 blocks
    barriernet_kernel<<<2048, BLK, 0, stream>>>(
        x, mean, stdv, b21, b22, W31, b31, W32, b32,
        w1q, (const u32x4*)frg_hi, out, /*zero=*/0);
}

// Round 6
// 124.277 us; speedup vs baseline: 4.3758x; 1.0385x over previous
//
#include <hip/hip_runtime.h>
#include <math.h>

typedef __attribute__((ext_vector_type(8))) short bf16x8;
typedef __attribute__((ext_vector_type(4))) float f32x4;
typedef __attribute__((ext_vector_type(4))) unsigned int u32x4;

#define BLK 256

// ws layout:
//   [0, 4096)      : W1 quad-packed fp32. For neuron c = t*32 + q*8 + j:
//                    float idx = ((t*8 + j)*4 + q)*8 -> {w0..w4, b1, 0, 0}.
//   [4096, 20480)  : W21/W22 bf16 fragments (16 frags x 1024 B)
// frag F = mat*8 + nt*4 + kt (mat: 0=W21, 1=W22)
// ushort index = F*512 + lane*8 + jj
// value = W[n = nt*16 + (lane&15)][k = kt*32 + (lane>>4)*8 + jj]
//
// MFMA operand order is SWAPPED vs the naive mapping: D = mfma(frg, au, acc)
// computes C'[n][m] = (W . h1^T): batch row m lands in C-cols (lane&15),
// neuron n in C-rows (q*4 + reg). A/B fragment layouts are symmetric, so the
// same au (h1) and frg (W) fragment data serve as B and A respectively.
// This makes the head dot-product lane-local (8 FMAs + 2 shuffles) instead of
// a 16-lane butterfly per reg.

__device__ __forceinline__ unsigned int rne_bf16_bits(float w) {
    unsigned int u = __builtin_bit_cast(unsigned int, w);
    u += 0x7fffu + ((u >> 16) & 1u);
    return u >> 16;
}

__global__ void setup_kernel(const float* __restrict__ W1, const float* __restrict__ b1,
                             const float* __restrict__ W21, const float* __restrict__ W22,
                             float* __restrict__ w1q, unsigned short* __restrict__ frg)
{
    int t = blockIdx.x * blockDim.x + threadIdx.x;   // 0..4095
    if (t < 128) {
        int c  = t;
        int tt = c >> 5, r = c & 31, qq = r >> 3, j = r & 7;
        float* dst = w1q + ((tt * 8 + j) * 4 + qq) * 8;
        #pragma unroll
        for (int f = 0; f < 5; ++f) dst[f] = W1[c * 5 + f];
        dst[5] = b1[c];
        dst[6] = 0.0f;
        dst[7] = 0.0f;
    }
    for (int e = t; e < 16 * 64 * 8; e += 4096) {
        int F = e >> 9, l = (e >> 3) & 63, j = e & 7;
        int mat = F >> 3, nt = (F >> 2) & 1, kt = F & 3;
        int n = nt * 16 + (l & 15);
        int k = kt * 32 + (l >> 4) * 8 + j;
        const float* W = mat ? W22 : W21;
        frg[e] = (unsigned short)rne_bf16_bits(W[n * 128 + k]);
    }
}

__global__ __launch_bounds__(BLK, 3) void barriernet_kernel(
    const float* __restrict__ x,
    const float* __restrict__ mean, const float* __restrict__ stdv,
    const float* __restrict__ b21, const float* __restrict__ b22,
    const float* __restrict__ W31, const float* __restrict__ b31,
    const float* __restrict__ W32, const float* __restrict__ b32,
    const float* __restrict__ w1q, const u32x4* __restrict__ frg,
    float* __restrict__ out, int zero)
{
    __shared__ u32x4 ldsF[1024];    // 16 frags x 64
    __shared__ float ldsX[1280];    // 256 rows x 5

    const int tid = threadIdx.x;
    #pragma unroll
    for (int i = 0; i < 4; ++i) ldsF[tid + i * BLK] = frg[tid + i * BLK];
    const float* xblk = x + (size_t)blockIdx.x * 1280;
    #pragma unroll
    for (int i = 0; i < 5; ++i) ldsX[tid + i * BLK] = xblk[tid + i * BLK];

    const int lane = tid & 63;
    const int wave = tid >> 6;
    const int m    = lane & 15;
    const int q    = lane >> 4;

    float sm_s[5], sm_m[5];
    #pragma unroll
    for (int f = 0; f < 5; ++f) { sm_s[f] = stdv[f]; sm_m[f] = mean[f]; }

    // Per-lane slices: n = nt*16 + q*4 + r  (r = accumulator reg index)
    const f32x4 b21a = *(const f32x4*)(b21 + q * 4);
    const f32x4 b21b = *(const f32x4*)(b21 + 16 + q * 4);
    const f32x4 b22a = *(const f32x4*)(b22 + q * 4);
    const f32x4 b22b = *(const f32x4*)(b22 + 16 + q * 4);
    const f32x4 w31a = *(const f32x4*)(W31 + q * 4);
    const f32x4 w31b = *(const f32x4*)(W31 + 16 + q * 4);
    const f32x4 w32a = *(const f32x4*)(W32 + q * 4);
    const f32x4 w32b = *(const f32x4*)(W32 + 16 + q * 4);
    const float b31s = b31[0], b32s = b32[0];

    __syncthreads();

    const size_t row0 = (size_t)blockIdx.x * 256;

    #pragma unroll 1
    for (int it = 0; it < 2; ++it) {
        const int tl0 = wave * 4 + it * 2;         // local tiles tl0, tl0+1

        float xf[2][5];
        #pragma unroll
        for (int T = 0; T < 2; ++T)
            #pragma unroll
            for (int f = 0; f < 5; ++f)
                xf[T][f] = ldsX[((tl0 + T) * 16 + m) * 5 + f];

        // ---- Phase A: layer 1 into fragment layout for both tiles ----
        const float* wz = w1q + it * zero;         // anti-hoist
        unsigned int au[2][4][4];
        #pragma unroll
        for (int t = 0; t < 4; ++t) {
            #pragma unroll
            for (int p = 0; p < 4; ++p) {
                const int g0 = ((t * 8 + p * 2) * 4 + q) * 8;
                const float4 a0 = *(const float4*)(wz + g0);
                const float4 a1 = *(const float4*)(wz + g0 + 4);
                const float4 c0 = *(const float4*)(wz + g0 + 32);
                const float4 c1 = *(const float4*)(wz + g0 + 36);
                #pragma unroll
                for (int T = 0; T < 2; ++T) {
                    float h0 = a1.y;
                    h0 = fmaf(xf[T][0], a0.x, h0);
                    h0 = fmaf(xf[T][1], a0.y, h0);
                    h0 = fmaf(xf[T][2], a0.z, h0);
                    h0 = fmaf(xf[T][3], a0.w, h0);
                    h0 = fmaf(xf[T][4], a1.x, h0);
                    h0 = fmaxf(h0, 0.0f);
                    float h1 = c1.y;
                    h1 = fmaf(xf[T][0], c0.x, h1);
                    h1 = fmaf(xf[T][1], c0.y, h1);
                    h1 = fmaf(xf[T][2], c0.z, h1);
                    h1 = fmaf(xf[T][3], c0.w, h1);
                    h1 = fmaf(xf[T][4], c1.x, h1);
                    h1 = fmaxf(h1, 0.0f);
                    au[T][t][p] = rne_bf16_bits(h0) | (rne_bf16_bits(h1) << 16);
                }
            }
        }

        // ---- GEMM2 (transposed): acc[T][c] = W_c . h1_T^T + bias ----
        f32x4 acc[2][4];
        #pragma unroll
        for (int T = 0; T < 2; ++T) {
            acc[T][0] = b21a; acc[T][1] = b21b;
            acc[T][2] = b22a; acc[T][3] = b22b;
        }
        const int fz = it * zero;                  // anti-hoist
        #pragma unroll
        for (int kt = 0; kt < 4; ++kt) {
            bf16x8 bw[4];
            #pragma unroll
            for (int c = 0; c < 4; ++c) {          // c = mat*2 + nt
                const int F = (c >> 1) * 8 + (c & 1) * 4 + kt;
                bw[c] = __builtin_bit_cast(bf16x8, ldsF[F * 64 + lane + fz]);
            }
            #pragma unroll
            for (int T = 0; T < 2; ++T) {
                u32x4 t4 = { au[T][kt][0], au[T][kt][1], au[T][kt][2], au[T][kt][3] };
                bf16x8 a = __builtin_bit_cast(bf16x8, t4);
                #pragma unroll
                for (int c = 0; c < 4; ++c)
                    acc[T][c] = __builtin_amdgcn_mfma_f32_16x16x32_bf16(bw[c], a, acc[T][c], 0, 0, 0);
            }
        }

        // ---- Heads: lane-local 8-FMA dot + 2 cross-quad shuffles ----
        #pragma unroll
        for (int T = 0; T < 2; ++T) {
            float s31 = 0.0f, s32 = 0.0f;
            #pragma unroll
            for (int r = 0; r < 4; ++r) {
                s31 = fmaf(fmaxf(acc[T][0][r], 0.0f), w31a[r], s31);
                s31 = fmaf(fmaxf(acc[T][1][r], 0.0f), w31b[r], s31);
                s32 = fmaf(fmaxf(acc[T][2][r], 0.0f), w32a[r], s32);
                s32 = fmaf(fmaxf(acc[T][3][r], 0.0f), w32b[r], s32);
            }
            s31 += __shfl_xor(s31, 16);
            s31 += __shfl_xor(s31, 32);
            s32 += __shfl_xor(s32, 16);
            s32 += __shfl_xor(s32, 32);

            // ---- Epilogue: every lane has row m's sums; lanes 0-15 store ----
            const float x31 = s31 + b31s;
            const float z   = s32 + b32s;
            const float x32 = 4.0f / (1.0f + __expf(-z));
            float x0[5];
            #pragma unroll
            for (int f = 0; f < 5; ++f) x0[f] = fmaf(xf[T][f], sm_s[f], sm_m[f]);
            const float h_ineq = (x0[1] - x0[3]) + x32 * (x0[0] - x0[2] - 1.8f * x0[3]);
            const float u_unc  = -x31;
            const float u      = (1.8f * u_unc <= h_ineq) ? u_unc : (h_ineq / 1.8f);
            if (lane < 16)
                out[row0 + (tl0 + T) * 16 + lane] = u;
        }
    }
}

extern "C" void kernel_launch(void* const* d_in, const int* in_sizes, int n_in,
                              void* d_out, int out_size, void* d_ws, size_t ws_size,
                              hipStream_t stream) {
    const float* x    = (const float*)d_in[0];
    const float* mean = (const float*)d_in[1];
    const float* stdv = (const float*)d_in[2];
    const float* W1   = (const float*)d_in[3];
    const float* b1   = (const float*)d_in[4];
    const float* W21  = (const float*)d_in[5];
    const float* b21  = (const float*)d_in[6];
    const float* W22  = (const float*)d_in[7];
    const float* b22  = (const float*)d_in[8];
    const float* W31  = (const float*)d_in[9];
    const float* b31  = (const float*)d_in[10];
    const float* W32  = (const float*)d_in[11];
    const float* b32  = (const float*)d_in[12];
    float* out = (float*)d_out;

    float* w1q = (float*)d_ws;
    unsigned short* frg = (unsigned short*)((char*)d_ws + 4096);

    setup_kernel<<<16, 256, 0, stream>>>(W1, b1, W21, W22, w1q, frg);

    // 524288 rows / 256 rows-per-block = 2048 blocks
    barriernet_kernel<<<2048, BLK, 0, stream>>>(
        x, mean, stdv, b21, b22, W31, b31, W32, b32,
        w1q, (const u32x4*)frg, out, /*zero=*/0);
}